// Round 1
// baseline (87.011 us; speedup 1.0000x reference)
//
#include <hip/hip_runtime.h>
#include <hip/hip_bf16.h>

// DenseGridNet: bilinear grid-feature gather + 3-layer MLP (5->64->64->3) + sigmoid.
// Strategy: bf16 MFMA (16x16x32) for all layers, wave-private LDS transposes,
// no cross-wave barriers (only lgkmcnt fences).

typedef __attribute__((ext_vector_type(8))) short bf16x8;   // 8 bf16 = 4 VGPRs
typedef __attribute__((ext_vector_type(4))) float f32x4;
typedef __attribute__((ext_vector_type(4))) unsigned int u32x4;

#define HID 64

static __device__ __forceinline__ unsigned short f2bf(float f) {
    __hip_bfloat16 h = __float2bfloat16(f);
    return __builtin_bit_cast(unsigned short, h);
}
static __device__ __forceinline__ void lds_fence() {
    // all LDS producer/consumer pairs here are intra-wave; DS pipe is in-order
    // per wave, so a completed-writes fence + compiler memory barrier suffices.
    asm volatile("s_waitcnt lgkmcnt(0)" ::: "memory");
}

#define MFMA16(a, b, c) __builtin_amdgcn_mfma_f32_16x16x32_bf16((a), (b), (c), 0, 0, 0)

__global__ __launch_bounds__(256, 3)
void dgn_kernel(const float* __restrict__ x, const float* __restrict__ emb,
                const float* __restrict__ w1, const float* __restrict__ b1,
                const float* __restrict__ w2, const float* __restrict__ b2,
                const float* __restrict__ w3, const float* __restrict__ b3,
                float* __restrict__ out, int n)
{
    // per-wave private LDS slices
    __shared__ __align__(16) short lds_in[4][64][8];    // in8 (bf16) per point
    __shared__ __align__(16) short lds_h[4][64][72];    // h1/h2, pad 64->72 (144B stride, 2-way banks = free)
    __shared__ __align__(16) float lds_o[4][192];       // output repack (64 pts x 3)

    const int tid  = threadIdx.x;
    const int wid  = tid >> 6;
    const int lane = tid & 63;
    const int cl   = lane & 15;   // MFMA col / A-row within tile
    const int kg   = lane >> 4;   // k-group 0..3

    short (*Lin)[8] = lds_in[wid];
    short (*Lh)[72] = lds_h[wid];
    float *Lo       = lds_o[wid];

    // ---------------- weight fragments (loaded once per block) ----------------
    // B-frag layout for mfma_f32_16x16x32_bf16: lane holds B[k = kg*8+j][col = nt*16+cl]
    bf16x8 w1f[4];            // layer1: rows 0..4 = w1, row 5 = b1 (via const-1 input), rest 0
    #pragma unroll
    for (int nt = 0; nt < 4; ++nt) {
        bf16x8 f = {};
        if (kg == 0) {
            int col = nt * 16 + cl;
            f[0] = (short)f2bf(w1[0 * HID + col]);
            f[1] = (short)f2bf(w1[1 * HID + col]);
            f[2] = (short)f2bf(w1[2 * HID + col]);
            f[3] = (short)f2bf(w1[3 * HID + col]);
            f[4] = (short)f2bf(w1[4 * HID + col]);
            f[5] = (short)f2bf(b1[col]);
        }
        w1f[nt] = f;
    }
    bf16x8 w2f[4][2];         // layer2: K=64 -> 2 k-steps
    #pragma unroll
    for (int nt = 0; nt < 4; ++nt) {
        #pragma unroll
        for (int ks = 0; ks < 2; ++ks) {
            bf16x8 f;
            #pragma unroll
            for (int j = 0; j < 8; ++j) {
                int k = ks * 32 + kg * 8 + j;
                f[j] = (short)f2bf(w2[k * HID + nt * 16 + cl]);
            }
            w2f[nt][ks] = f;
        }
    }
    bf16x8 w3f[2];            // layer3: 3 cols, padded to 16
    #pragma unroll
    for (int ks = 0; ks < 2; ++ks) {
        bf16x8 f = {};
        if (cl < 3) {
            #pragma unroll
            for (int j = 0; j < 8; ++j) {
                int k = ks * 32 + kg * 8 + j;
                f[j] = (short)f2bf(w3[k * 3 + cl]);
            }
        }
        w3f[ks] = f;
    }
    float b2v[4];
    #pragma unroll
    for (int nt = 0; nt < 4; ++nt) b2v[nt] = b2[nt * 16 + cl];
    const float b3v = (cl < 3) ? b3[cl] : 0.0f;

    const f32x4* emb4 = (const f32x4*)emb;

    // ---------------- main loop: 64 points per wave per iteration ----------------
    for (int base = blockIdx.x * 256; base < n; base += gridDim.x * 256) {
        const int wbase = base + wid * 64;
        const int pt    = wbase + lane;

        float idf = 0.0f, u = 0.0f, vv = 0.0f;
        if (pt < n) {
            const float* xp = x + 3 * pt;
            idf = xp[0]; u = xp[1]; vv = xp[2];
        }

        // bilinear grid features (exact reference formulas, fp32)
        int x0 = (int)(u * 1024.0f); if (x0 == 1024) x0 = 0;
        int x1i = (x0 + 1 == 1024) ? 1023 : x0 + 1;
        int y0 = (int)(vv * 1024.0f);
        int y1 = (y0 + 1 == 1024) ? 1023 : y0 + 1;
        float wx = u  * 1024.0f - (float)x0;
        float wy = vv * 1024.0f - (float)y0;

        f32x4 v00 = emb4[y0 * 1024 + x0];
        f32x4 v10 = emb4[y0 * 1024 + x1i];
        f32x4 v01 = emb4[y1 * 1024 + x0];
        f32x4 v11 = emb4[y1 * 1024 + x1i];
        f32x4 vup = v00 * (1.0f - wx) + v10 * wx;
        f32x4 vdn = v01 * (1.0f - wx) + v11 * wx;
        f32x4 g   = vup * (1.0f - wy) + vdn * wy;

        // pack in8 = [idf, g0..g3, 1, 0, 0] as bf16, write 16B to LDS
        unsigned q0 = (unsigned)f2bf(idf)  | ((unsigned)f2bf(g[0]) << 16);
        unsigned q1 = (unsigned)f2bf(g[1]) | ((unsigned)f2bf(g[2]) << 16);
        unsigned q2 = (unsigned)f2bf(g[3]) | (0x3F80u << 16);   // 1.0bf16
        u32x4 inq = {q0, q1, q2, 0u};
        *(u32x4*)(&Lin[lane][0]) = inq;

        lds_fence();

        // -------- layer 1: K=32 (rows 5.. zero-padded) --------
        f32x4 acc1[4][4] = {};
        #pragma unroll
        for (int mt = 0; mt < 4; ++mt) {
            bf16x8 af = {};
            if (kg == 0) af = *(const bf16x8*)(&Lin[mt * 16 + cl][0]);
            #pragma unroll
            for (int nt = 0; nt < 4; ++nt)
                acc1[mt][nt] = MFMA16(af, w1f[nt], acc1[mt][nt]);
        }
        // relu, h1 -> LDS (C layout: row = kg*4+r, col = cl)
        #pragma unroll
        for (int mt = 0; mt < 4; ++mt)
            #pragma unroll
            for (int nt = 0; nt < 4; ++nt)
                #pragma unroll
                for (int r = 0; r < 4; ++r)
                    Lh[mt * 16 + kg * 4 + r][nt * 16 + cl] =
                        (short)f2bf(fmaxf(acc1[mt][nt][r], 0.0f));

        lds_fence();

        // -------- layer 2: K=64 --------
        f32x4 acc2[4][4] = {};
        #pragma unroll
        for (int mt = 0; mt < 4; ++mt) {
            bf16x8 a0 = *(const bf16x8*)(&Lh[mt * 16 + cl][kg * 8]);
            bf16x8 a1 = *(const bf16x8*)(&Lh[mt * 16 + cl][32 + kg * 8]);
            #pragma unroll
            for (int nt = 0; nt < 4; ++nt) {
                acc2[mt][nt] = MFMA16(a0, w2f[nt][0], acc2[mt][nt]);
                acc2[mt][nt] = MFMA16(a1, w2f[nt][1], acc2[mt][nt]);
            }
        }
        #pragma unroll
        for (int mt = 0; mt < 4; ++mt)
            #pragma unroll
            for (int nt = 0; nt < 4; ++nt)
                #pragma unroll
                for (int r = 0; r < 4; ++r)
                    Lh[mt * 16 + kg * 4 + r][nt * 16 + cl] =
                        (short)f2bf(fmaxf(acc2[mt][nt][r] + b2v[nt], 0.0f));

        lds_fence();

        // -------- layer 3: K=64, 3 output cols --------
        f32x4 acc3[4] = {};
        #pragma unroll
        for (int mt = 0; mt < 4; ++mt) {
            bf16x8 a0 = *(const bf16x8*)(&Lh[mt * 16 + cl][kg * 8]);
            bf16x8 a1 = *(const bf16x8*)(&Lh[mt * 16 + cl][32 + kg * 8]);
            acc3[mt] = MFMA16(a0, w3f[0], acc3[mt]);
            acc3[mt] = MFMA16(a1, w3f[1], acc3[mt]);
        }
        if (cl < 3) {
            #pragma unroll
            for (int mt = 0; mt < 4; ++mt)
                #pragma unroll
                for (int r = 0; r < 4; ++r) {
                    float lg = acc3[mt][r] + b3v;
                    float s  = 1.0f / (1.0f + __expf(-lg));
                    Lo[(mt * 16 + kg * 4 + r) * 3 + cl] = s;
                }
        }

        lds_fence();

        // coalesced output store: 3 consecutive floats per lane
        if (pt < n) {
            int ob = pt * 3;
            out[ob + 0] = Lo[lane * 3 + 0];
            out[ob + 1] = Lo[lane * 3 + 1];
            out[ob + 2] = Lo[lane * 3 + 2];
        }
    }
}

extern "C" void kernel_launch(void* const* d_in, const int* in_sizes, int n_in,
                              void* d_out, int out_size, void* d_ws, size_t ws_size,
                              hipStream_t stream) {
    const float* x   = (const float*)d_in[0];
    const float* emb = (const float*)d_in[1];
    const float* w1  = (const float*)d_in[2];
    const float* b1  = (const float*)d_in[3];
    const float* w2  = (const float*)d_in[4];
    const float* b2  = (const float*)d_in[5];
    const float* w3  = (const float*)d_in[6];
    const float* b3  = (const float*)d_in[7];
    float* out = (float*)d_out;

    int n = in_sizes[0] / 3;
    int nblk = (n + 255) / 256;
    if (nblk > 2048) nblk = 2048;   // grid-stride: 4 iters/block at N=2^21
    dgn_kernel<<<dim3(nblk), dim3(256), 0, stream>>>(x, emb, w1, b1, w2, b2, w3, b3, out, n);
}